// Round 1
// baseline (81330.841 us; speedup 1.0000x reference)
//
#include <hip/hip_runtime.h>

// LSTM (S=16384, I=64, H=1024) -> ReLU -> FC(1024->128) -> ReLU -> FC(128->1), last step only.
// Strategy: persistent cooperative-style kernel, W_hh register-resident, per-step
// device-wide h broadcast via LLC (agent-scope atomics) + per-block monotonic flags.

#define S_LEN 16384
#define I_DIM 64
#define H_DIM 1024
#define NBLK  256      // 1 block per CU -> co-residency
#define NTHR  256
#define FSTRIDE 16     // flag padding: 16 ints = 64 B

__device__ __forceinline__ float sigmoidf_(float x) { return 1.0f / (1.0f + __expf(-x)); }
__device__ __forceinline__ float tanh_fast(float x) { return 1.0f - 2.0f / (__expf(2.0f * x) + 1.0f); }

// Block b owns h-indices jb = 4b..4b+3 (16 gate rows: gate*1024 + jb + jj).
// Wave w (0..3) = gate w (i,f,g,o). Lane c covers k = s*256 + c*4 + j (s=0..3, j=0..3)
// of the 1024-wide h-dot, plus (c<16) the 64-wide x-dot k = c*4+j.
__global__ __launch_bounds__(NTHR, 2) void lstm_persistent(
    const float* __restrict__ xseq,   // [S, 64]
    const float* __restrict__ W_ih,   // [4096, 64]
    const float* __restrict__ W_hh,   // [4096, 1024]
    const float* __restrict__ b_ih,   // [4096]
    const float* __restrict__ b_hh,   // [4096]
    float* __restrict__ ws)           // hbuf[2][1024] floats, then flags[NBLK*FSTRIDE] ints
{
    const int b   = blockIdx.x;
    const int tid = threadIdx.x;
    const int w   = tid >> 6;   // wave id = gate id
    const int c   = tid & 63;   // lane id

    float* hbuf  = ws;                         // [2][1024]
    int*   flags = (int*)(ws + 2 * H_DIM);     // poison 0xAAAAAAAA is negative -> no init needed

    __shared__ float4 h_stage[H_DIM / 4];
    __shared__ float4 x_stage[2][I_DIM / 4];
    __shared__ float  gs[16];       // gate sums, index = gate*4 + jj
    __shared__ float  bias_s[16];
    __shared__ float  h_out[4];
    __shared__ float  c_state[4];

    // ---- one-time: weights into registers (coalesced float4 loads) ----
    float4 wh[4][4];
    float4 wi[4];
    #pragma unroll
    for (int jj = 0; jj < 4; ++jj) {
        const int grow = w * H_DIM + 4 * b + jj;
        const float4* wr = (const float4*)(W_hh + (size_t)grow * H_DIM);
        #pragma unroll
        for (int s = 0; s < 4; ++s) wh[jj][s] = wr[s * 64 + c];
        if (c < 16) wi[jj] = ((const float4*)(W_ih + (size_t)grow * I_DIM))[c];
        else        wi[jj] = make_float4(0.f, 0.f, 0.f, 0.f);
    }
    if (tid < 16) {
        const int grow = (tid >> 2) * H_DIM + 4 * b + (tid & 3);
        bias_s[tid] = b_ih[grow] + b_hh[grow];
    }
    if (tid < 4) c_state[tid] = 0.0f;
    h_stage[tid] = make_float4(0.f, 0.f, 0.f, 0.f);   // h_{-1} = 0
    if (tid < 16) x_stage[0][tid] = ((const float4*)xseq)[tid];  // x_0
    __syncthreads();

    for (int t = 0; t < S_LEN; ++t) {
        // prefetch x_{t+1} (no serial dependency)
        float4 xpre;
        const bool pf = (tid < 16) && (t + 1 < S_LEN);
        if (pf) xpre = ((const float4*)(xseq + (size_t)(t + 1) * I_DIM))[tid];

        // ---- gate dot products: W_hh . h_{t-1} (+ W_ih . x_t on lanes 0..15) ----
        float acc[4] = {0.f, 0.f, 0.f, 0.f};
        #pragma unroll
        for (int s = 0; s < 4; ++s) {
            const float4 hv = h_stage[s * 64 + c];
            #pragma unroll
            for (int jj = 0; jj < 4; ++jj) {
                acc[jj] = fmaf(wh[jj][s].x, hv.x, acc[jj]);
                acc[jj] = fmaf(wh[jj][s].y, hv.y, acc[jj]);
                acc[jj] = fmaf(wh[jj][s].z, hv.z, acc[jj]);
                acc[jj] = fmaf(wh[jj][s].w, hv.w, acc[jj]);
            }
        }
        if (c < 16) {
            const float4 xv = x_stage[t & 1][c];
            #pragma unroll
            for (int jj = 0; jj < 4; ++jj) {
                acc[jj] = fmaf(wi[jj].x, xv.x, acc[jj]);
                acc[jj] = fmaf(wi[jj].y, xv.y, acc[jj]);
                acc[jj] = fmaf(wi[jj].z, xv.z, acc[jj]);
                acc[jj] = fmaf(wi[jj].w, xv.w, acc[jj]);
            }
        }
        // full-wave butterfly reduction (all 64 lanes end with the row sum)
        #pragma unroll
        for (int jj = 0; jj < 4; ++jj) {
            #pragma unroll
            for (int off = 32; off > 0; off >>= 1)
                acc[jj] += __shfl_xor(acc[jj], off, 64);
        }
        if (c == 0) {
            #pragma unroll
            for (int jj = 0; jj < 4; ++jj) gs[w * 4 + jj] = acc[jj];
        }
        if (pf) x_stage[(t + 1) & 1][tid] = xpre;
        __syncthreads();

        // ---- activations + state update (4 threads, one h-index each) ----
        if (tid < 4) {
            const int j = tid;
            const float pi  = gs[0  + j] + bias_s[0  + j];
            const float pfg = gs[4  + j] + bias_s[4  + j];
            const float pg  = gs[8  + j] + bias_s[8  + j];
            const float po  = gs[12 + j] + bias_s[12 + j];
            const float ig = sigmoidf_(pi);
            const float fg = sigmoidf_(pfg);
            const float gg = tanh_fast(pg);
            const float og = sigmoidf_(po);
            const float cn = fg * c_state[j] + ig * gg;
            c_state[j] = cn;
            h_out[j] = og * tanh_fast(cn);
        }
        __syncthreads();

        // ---- publish h slice: relaxed agent data stores + release flag (single thread
        //      => formally ordered; agent scope bypasses non-coherent per-XCD L2) ----
        if (tid == 0) {
            float* dst = hbuf + (t & 1) * H_DIM + 4 * b;
            #pragma unroll
            for (int jj = 0; jj < 4; ++jj)
                __hip_atomic_store(dst + jj, h_out[jj], __ATOMIC_RELAXED, __HIP_MEMORY_SCOPE_AGENT);
            __hip_atomic_store(&flags[b * FSTRIDE], t + 1, __ATOMIC_RELEASE, __HIP_MEMORY_SCOPE_AGENT);
        }

        // ---- barrier: wave 0 polls 4 flags/lane (relaxed, batched loads) ----
        if (w == 0) {
            const int tgt = t + 1;
            for (;;) {
                bool ok = true;
                #pragma unroll
                for (int u = 0; u < 4; ++u) {
                    const int v = __hip_atomic_load(&flags[(c * 4 + u) * FSTRIDE],
                                                    __ATOMIC_RELAXED, __HIP_MEMORY_SCOPE_AGENT);
                    ok = ok && (v >= tgt);
                }
                if (ok) break;
                __builtin_amdgcn_s_sleep(2);
            }
        }
        __syncthreads();

        // ---- re-stage full h_t into LDS (agent loads -> always fresh from LLC) ----
        {
            const float* src = hbuf + (t & 1) * H_DIM + tid * 4;
            const float v0 = __hip_atomic_load(src + 0, __ATOMIC_RELAXED, __HIP_MEMORY_SCOPE_AGENT);
            const float v1 = __hip_atomic_load(src + 1, __ATOMIC_RELAXED, __HIP_MEMORY_SCOPE_AGENT);
            const float v2 = __hip_atomic_load(src + 2, __ATOMIC_RELAXED, __HIP_MEMORY_SCOPE_AGENT);
            const float v3 = __hip_atomic_load(src + 3, __ATOMIC_RELAXED, __HIP_MEMORY_SCOPE_AGENT);
            h_stage[tid] = make_float4(v0, v1, v2, v3);
        }
        __syncthreads();
    }
}

// Final head: out = fc2( relu( fc1( relu(h_{S-1}) ) ) ). h_{S-1} is in hbuf slot 1
// (S-1 = 16383 is odd). Kernel-boundary ordering makes plain loads safe.
__global__ __launch_bounds__(256) void fc_head(
    const float* __restrict__ ws,
    const float* __restrict__ fc1_w,  // [128, 1024]
    const float* __restrict__ fc1_b,  // [128]
    const float* __restrict__ fc2_w,  // [128]
    const float* __restrict__ fc2_b,  // [1]
    float* __restrict__ out)
{
    const int tid = threadIdx.x;
    __shared__ float4 hr4[H_DIM / 4];
    __shared__ float  partial[256];
    __shared__ float  r1[128];

    const float* hfin = ws + H_DIM;   // slot (S-1)&1 == 1
    float4 hv = ((const float4*)hfin)[tid];
    hv.x = fmaxf(hv.x, 0.f); hv.y = fmaxf(hv.y, 0.f);
    hv.z = fmaxf(hv.z, 0.f); hv.w = fmaxf(hv.w, 0.f);
    hr4[tid] = hv;
    __syncthreads();

    const int row = tid & 127, half = tid >> 7;
    const float4* wrow = (const float4*)(fc1_w + (size_t)row * H_DIM) + half * 128;
    float a0 = 0.f, a1 = 0.f;
    #pragma unroll 4
    for (int i = 0; i < 128; i += 2) {
        const float4 w0 = wrow[i],     h0 = hr4[half * 128 + i];
        const float4 w1 = wrow[i + 1], h1 = hr4[half * 128 + i + 1];
        a0 += w0.x * h0.x + w0.y * h0.y + w0.z * h0.z + w0.w * h0.w;
        a1 += w1.x * h1.x + w1.y * h1.y + w1.z * h1.z + w1.w * h1.w;
    }
    partial[tid] = a0 + a1;
    __syncthreads();
    if (tid < 128) {
        const float s = partial[tid] + partial[tid + 128] + fc1_b[tid];
        r1[tid] = fmaxf(s, 0.f);
    }
    __syncthreads();
    if (tid < 64) {
        float v = r1[tid] * fc2_w[tid] + r1[tid + 64] * fc2_w[tid + 64];
        #pragma unroll
        for (int off = 32; off > 0; off >>= 1) v += __shfl_xor(v, off, 64);
        if (tid == 0) out[0] = v + fc2_b[0];
    }
}

extern "C" void kernel_launch(void* const* d_in, const int* in_sizes, int n_in,
                              void* d_out, int out_size, void* d_ws, size_t ws_size,
                              hipStream_t stream) {
    (void)in_sizes; (void)n_in; (void)out_size; (void)ws_size;
    const float* xseq  = (const float*)d_in[0];
    const float* W_ih  = (const float*)d_in[1];
    const float* W_hh  = (const float*)d_in[2];
    const float* b_ih  = (const float*)d_in[3];
    const float* b_hh  = (const float*)d_in[4];
    const float* fc1_w = (const float*)d_in[5];
    const float* fc1_b = (const float*)d_in[6];
    const float* fc2_w = (const float*)d_in[7];
    const float* fc2_b = (const float*)d_in[8];
    float* ws = (float*)d_ws;

    lstm_persistent<<<NBLK, NTHR, 0, stream>>>(xseq, W_ih, W_hh, b_ih, b_hh, ws);
    fc_head<<<1, 256, 0, stream>>>(ws, fc1_w, fc1_b, fc2_w, fc2_b, (float*)d_out);
}

// Round 2
// 42815.503 us; speedup vs baseline: 1.8996x; 1.8996x over previous
//
#include <hip/hip_runtime.h>

// LSTM (S=16384, I=64, H=1024) -> ReLU -> FC(1024->128) -> ReLU -> FC(128->1), last step only.
// Persistent kernel, W_hh register-resident across 64 blocks.
// Per-step device-wide h broadcast via self-validating (tag,value) 8-byte pairs
// stored/loaded with 64-bit relaxed agent-scope atomics (single LLC round trip,
// no fences). Double-buffered by step parity; tag equality == freshness proof.

#define S_LEN 16384
#define I_DIM 64
#define H_DIM 1024
#define NBLK  64
#define NTHR  1024

__device__ __forceinline__ float sigmoidf_(float x) { return 1.0f / (1.0f + __expf(-x)); }
__device__ __forceinline__ float tanh_fast(float x) { return 1.0f - 2.0f / (__expf(2.0f * x) + 1.0f); }

// Block b owns h-indices 16b..16b+15 (64 gate rows). Wave w (0..15): gate g=w>>2,
// rows r = (w&3)*4 + q, q=0..3. Lane c covers h-cols {s*256 + 4c .. +3}, s=0..3
// (consecutive-lane float4 LDS reads -> 0 bank conflicts, verified R1), plus
// x-col c (one float per row).
__global__ __launch_bounds__(NTHR, 4) void lstm_persistent(
    const float* __restrict__ xseq,   // [S, 64]
    const float* __restrict__ W_ih,   // [4096, 64]
    const float* __restrict__ W_hh,   // [4096, 1024]
    const float* __restrict__ b_ih,   // [4096]
    const float* __restrict__ b_hh,   // [4096]
    unsigned long long* __restrict__ pairs)  // [2][1024] (tag<<32 | float_bits)
{
    const int b   = blockIdx.x;
    const int tid = threadIdx.x;
    const int w   = tid >> 6;        // wave id 0..15
    const int c   = tid & 63;        // lane id
    const int g   = w >> 2;          // gate id (i,f,g,o)
    const int r0  = (w & 3) * 4;     // first of this wave's 4 rows (within 16)

    __shared__ float4 h_stage[H_DIM / 4];
    __shared__ float  x_stage[2][I_DIM];
    __shared__ float  gs[64];        // gate sums, index = gate*16 + row
    __shared__ float  bias_s[64];

    // ---- one-time: weights into registers (coalesced float4 loads) ----
    float4 wh[4][4];
    float  wi[4];
    #pragma unroll
    for (int q = 0; q < 4; ++q) {
        const int grow = g * H_DIM + 16 * b + r0 + q;
        const float4* wr = (const float4*)(W_hh + (size_t)grow * H_DIM);
        #pragma unroll
        for (int s = 0; s < 4; ++s) wh[q][s] = wr[s * 64 + c];
        wi[q] = W_ih[(size_t)grow * I_DIM + c];
    }
    if (tid < 64) {
        const int grow = (tid >> 4) * H_DIM + 16 * b + (tid & 15);
        bias_s[tid] = b_ih[grow] + b_hh[grow];
    }
    float cst = 0.0f;   // cell state, held in registers of threads tid<16
    if (tid < H_DIM / 4) h_stage[tid] = make_float4(0.f, 0.f, 0.f, 0.f);  // h_{-1}=0
    if (tid < 16) ((float4*)x_stage[0])[tid] = ((const float4*)xseq)[tid];
    __syncthreads();

    for (int t = 0; t < S_LEN; ++t) {
        // prefetch x_{t+1} into the other parity slot (no serial dependency)
        if (tid < 16 && t + 1 < S_LEN)
            ((float4*)x_stage[(t + 1) & 1])[tid] =
                ((const float4*)(xseq + (size_t)(t + 1) * I_DIM))[tid];

        // ---- gate dot products: W_hh . h_{t-1} + W_ih . x_t ----
        float acc[4] = {0.f, 0.f, 0.f, 0.f};
        #pragma unroll
        for (int s = 0; s < 4; ++s) {
            const float4 hv = h_stage[s * 64 + c];
            #pragma unroll
            for (int q = 0; q < 4; ++q) {
                acc[q] = fmaf(wh[q][s].x, hv.x, acc[q]);
                acc[q] = fmaf(wh[q][s].y, hv.y, acc[q]);
                acc[q] = fmaf(wh[q][s].z, hv.z, acc[q]);
                acc[q] = fmaf(wh[q][s].w, hv.w, acc[q]);
            }
        }
        {
            const float xv = x_stage[t & 1][c];
            #pragma unroll
            for (int q = 0; q < 4; ++q) acc[q] = fmaf(wi[q], xv, acc[q]);
        }
        // full-wave butterfly reduction
        #pragma unroll
        for (int q = 0; q < 4; ++q) {
            #pragma unroll
            for (int off = 32; off > 0; off >>= 1)
                acc[q] += __shfl_xor(acc[q], off, 64);
        }
        if (c == 0) {
            #pragma unroll
            for (int q = 0; q < 4; ++q) gs[g * 16 + r0 + q] = acc[q];
        }
        __syncthreads();

        // ---- activations + state update + publish (16 threads, 1 h-idx each) ----
        if (tid < 16) {
            const float pi  = gs[tid]      + bias_s[tid];
            const float pfg = gs[16 + tid] + bias_s[16 + tid];
            const float pg  = gs[32 + tid] + bias_s[32 + tid];
            const float po  = gs[48 + tid] + bias_s[48 + tid];
            const float ig = sigmoidf_(pi);
            const float fg = sigmoidf_(pfg);
            const float gg = tanh_fast(pg);
            const float og = sigmoidf_(po);
            cst = fg * cst + ig * gg;
            const float h = og * tanh_fast(cst);
            const unsigned long long pk =
                ((unsigned long long)(unsigned)(t + 1) << 32) | (unsigned long long)__float_as_uint(h);
            __hip_atomic_store(&pairs[(size_t)(t & 1) * H_DIM + 16 * b + tid], pk,
                               __ATOMIC_RELAXED, __HIP_MEMORY_SCOPE_AGENT);
        }

        // ---- poll: thread tid waits for pair tid (tag+data in one 8B word) ----
        {
            const unsigned tag = (unsigned)(t + 1);
            const unsigned long long* p = &pairs[(size_t)(t & 1) * H_DIM + tid];
            unsigned long long pk;
            for (;;) {
                pk = __hip_atomic_load(p, __ATOMIC_RELAXED, __HIP_MEMORY_SCOPE_AGENT);
                if ((unsigned)(pk >> 32) == tag) break;
                __builtin_amdgcn_s_sleep(1);
            }
            ((float*)h_stage)[tid] = __uint_as_float((unsigned)pk);
        }
        __syncthreads();
    }
}

// Final head: out = fc2( relu( fc1( relu(h_{S-1}) ) ) ). h_{S-1} is in pairs
// slot 1 ((S-1)&1). Kernel-boundary ordering makes plain loads safe.
__global__ __launch_bounds__(256) void fc_head(
    const unsigned long long* __restrict__ pairs,
    const float* __restrict__ fc1_w,  // [128, 1024]
    const float* __restrict__ fc1_b,  // [128]
    const float* __restrict__ fc2_w,  // [128]
    const float* __restrict__ fc2_b,  // [1]
    float* __restrict__ out)
{
    const int tid = threadIdx.x;
    __shared__ float4 hr4[H_DIM / 4];
    __shared__ float  partial[256];
    __shared__ float  r1[128];

    // extract floats from (tag,value) pairs, slot 1
    const uint4* pp = (const uint4*)(pairs + H_DIM) + 2 * tid;  // uint4 = 2 pairs
    const uint4 pa = pp[0], pb = pp[1];
    float4 hv = make_float4(__uint_as_float(pa.x), __uint_as_float(pa.z),
                            __uint_as_float(pb.x), __uint_as_float(pb.z));
    hv.x = fmaxf(hv.x, 0.f); hv.y = fmaxf(hv.y, 0.f);
    hv.z = fmaxf(hv.z, 0.f); hv.w = fmaxf(hv.w, 0.f);
    hr4[tid] = hv;
    __syncthreads();

    const int row = tid & 127, half = tid >> 7;
    const float4* wrow = (const float4*)(fc1_w + (size_t)row * H_DIM) + half * 128;
    float a0 = 0.f, a1 = 0.f;
    #pragma unroll 4
    for (int i = 0; i < 128; i += 2) {
        const float4 w0 = wrow[i],     h0 = hr4[half * 128 + i];
        const float4 w1 = wrow[i + 1], h1 = hr4[half * 128 + i + 1];
        a0 += w0.x * h0.x + w0.y * h0.y + w0.z * h0.z + w0.w * h0.w;
        a1 += w1.x * h1.x + w1.y * h1.y + w1.z * h1.z + w1.w * h1.w;
    }
    partial[tid] = a0 + a1;
    __syncthreads();
    if (tid < 128) {
        const float s = partial[tid] + partial[tid + 128] + fc1_b[tid];
        r1[tid] = fmaxf(s, 0.f);
    }
    __syncthreads();
    if (tid < 64) {
        float v = r1[tid] * fc2_w[tid] + r1[tid + 64] * fc2_w[tid + 64];
        #pragma unroll
        for (int off = 32; off > 0; off >>= 1) v += __shfl_xor(v, off, 64);
        if (tid == 0) out[0] = v + fc2_b[0];
    }
}

extern "C" void kernel_launch(void* const* d_in, const int* in_sizes, int n_in,
                              void* d_out, int out_size, void* d_ws, size_t ws_size,
                              hipStream_t stream) {
    (void)in_sizes; (void)n_in; (void)out_size; (void)ws_size;
    const float* xseq  = (const float*)d_in[0];
    const float* W_ih  = (const float*)d_in[1];
    const float* W_hh  = (const float*)d_in[2];
    const float* b_ih  = (const float*)d_in[3];
    const float* b_hh  = (const float*)d_in[4];
    const float* fc1_w = (const float*)d_in[5];
    const float* fc1_b = (const float*)d_in[6];
    const float* fc2_w = (const float*)d_in[7];
    const float* fc2_b = (const float*)d_in[8];
    unsigned long long* pairs = (unsigned long long*)d_ws;

    lstm_persistent<<<NBLK, NTHR, 0, stream>>>(xseq, W_ih, W_hh, b_ih, b_hh, pairs);
    fc_head<<<1, 256, 0, stream>>>(pairs, fc1_w, fc1_b, fc2_w, fc2_b, (float*)d_out);
}

// Round 3
// 39718.707 us; speedup vs baseline: 2.0477x; 1.0780x over previous
//
#include <hip/hip_runtime.h>
#include <hip/hip_fp16.h>

// LSTM (S=16384, I=64, H=1024) -> ReLU -> FC(1024->128) -> ReLU -> FC(128->1), last step only.
// Persistent kernel, W_hh register-resident across 64 blocks (1/CU-quarter of device).
// Per-step device-wide h broadcast via self-validating 4-byte (tag16, fp16) pairs,
// relaxed agent-scope atomics: poll IS the data read, one LLC round trip, no fences.
// Producer's 16 pairs = exactly one 64-B cacheline. Own-slice bypasses fabric via LDS.

#define S_LEN 16384
#define I_DIM 64
#define H_DIM 1024
#define NBLK  64
#define NTHR  1024

__device__ __forceinline__ float sigmoidf_(float x) { return 1.0f / (1.0f + __expf(-x)); }
__device__ __forceinline__ float tanh_fast(float x) { return 1.0f - 2.0f / (__expf(2.0f * x) + 1.0f); }

__device__ __forceinline__ unsigned pack_pair(unsigned tag, float h) {
    return (tag << 16) | (unsigned)__half_as_ushort(__float2half(h));
}
__device__ __forceinline__ float unpack_val(unsigned pk) {
    return __half2float(__ushort_as_half((unsigned short)(pk & 0xFFFFu)));
}

// Block b owns h-indices 16b..16b+15 (64 gate rows). Wave w (0..15): gate g=w>>2,
// rows r0=(w&3)*4..+3. Lane c covers h-cols {s*256 + 4c .. +3}, s=0..3 (float4 LDS
// reads, 0 bank conflicts verified R1/R2), plus x-col c.
__global__ __launch_bounds__(NTHR, 4) void lstm_persistent(
    const float* __restrict__ xseq,   // [S, 64]
    const float* __restrict__ W_ih,   // [4096, 64]
    const float* __restrict__ W_hh,   // [4096, 1024]
    const float* __restrict__ b_ih,   // [4096]
    const float* __restrict__ b_hh,   // [4096]
    unsigned* __restrict__ pairs)     // [2][1024] 4-B pairs (tag16<<16 | fp16 bits)
{
    const int b   = blockIdx.x;
    const int tid = threadIdx.x;
    const int w   = tid >> 6;        // wave id 0..15
    const int c   = tid & 63;        // lane id
    const int g   = w >> 2;          // gate id (i,f,g,o)
    const int r0  = (w & 3) * 4;     // first of this wave's 4 rows (within 16)

    __shared__ float4 h_stage[H_DIM / 4];
    __shared__ float  x_stage[2][I_DIM];
    __shared__ float  gs[64];        // gate sums, index = gate*16 + row
    __shared__ float  bias_s[64];

    // ---- one-time: weights into registers (coalesced float4 loads) ----
    float4 wh[4][4];
    float  wi[4];
    #pragma unroll
    for (int q = 0; q < 4; ++q) {
        const int grow = g * H_DIM + 16 * b + r0 + q;
        const float4* wr = (const float4*)(W_hh + (size_t)grow * H_DIM);
        #pragma unroll
        for (int s = 0; s < 4; ++s) wh[q][s] = wr[s * 64 + c];
        wi[q] = W_ih[(size_t)grow * I_DIM + c];
    }
    if (tid < 64) {
        const int grow = (tid >> 4) * H_DIM + 16 * b + (tid & 15);
        bias_s[tid] = b_ih[grow] + b_hh[grow];
    }
    float cst = 0.0f;   // cell state in registers of threads tid<16
    if (tid < H_DIM / 4) h_stage[tid] = make_float4(0.f, 0.f, 0.f, 0.f);  // h_{-1}=0
    if (tid < 16) ((float4*)x_stage[0])[tid] = ((const float4*)xseq)[tid];
    const bool own = (tid >> 4) == b;   // this thread's pair is produced by this block
    __syncthreads();

    for (int t = 0; t < S_LEN; ++t) {
        // prefetch x_{t+1} into the other parity slot (no serial dependency)
        if (tid < 16 && t + 1 < S_LEN)
            ((float4*)x_stage[(t + 1) & 1])[tid] =
                ((const float4*)(xseq + (size_t)(t + 1) * I_DIM))[tid];

        // ---- gate dot products: W_hh . h_{t-1} + W_ih . x_t ----
        float acc[4] = {0.f, 0.f, 0.f, 0.f};
        #pragma unroll
        for (int s = 0; s < 4; ++s) {
            const float4 hv = h_stage[s * 64 + c];
            #pragma unroll
            for (int q = 0; q < 4; ++q) {
                acc[q] = fmaf(wh[q][s].x, hv.x, acc[q]);
                acc[q] = fmaf(wh[q][s].y, hv.y, acc[q]);
                acc[q] = fmaf(wh[q][s].z, hv.z, acc[q]);
                acc[q] = fmaf(wh[q][s].w, hv.w, acc[q]);
            }
        }
        {
            const float xv = x_stage[t & 1][c];
            #pragma unroll
            for (int q = 0; q < 4; ++q) acc[q] = fmaf(wi[q], xv, acc[q]);
        }
        // full-wave butterfly reduction
        #pragma unroll
        for (int q = 0; q < 4; ++q) {
            #pragma unroll
            for (int off = 32; off > 0; off >>= 1)
                acc[q] += __shfl_xor(acc[q], off, 64);
        }
        if (c == 0) {
            #pragma unroll
            for (int q = 0; q < 4; ++q) gs[g * 16 + r0 + q] = acc[q];
        }
        __syncthreads();

        // ---- activations + state update + publish (16 threads, 1 h-idx each) ----
        if (tid < 16) {
            const float pi  = gs[tid]      + bias_s[tid];
            const float pfg = gs[16 + tid] + bias_s[16 + tid];
            const float pg  = gs[32 + tid] + bias_s[32 + tid];
            const float po  = gs[48 + tid] + bias_s[48 + tid];
            const float ig = sigmoidf_(pi);
            const float fg = sigmoidf_(pfg);
            const float gg = tanh_fast(pg);
            const float og = sigmoidf_(po);
            cst = fg * cst + ig * gg;
            const float h = og * tanh_fast(cst);
            const unsigned pk = pack_pair((unsigned)(t + 1), h);
            // one 64-B line per block: 16 contiguous 4-B stores from lanes 0..15
            __hip_atomic_store(&pairs[(size_t)(t & 1) * H_DIM + 16 * b + tid], pk,
                               __ATOMIC_RELAXED, __HIP_MEMORY_SCOPE_AGENT);
            // own-slice LDS bypass: consistent fp16-rounded value, no fabric trip
            ((float*)h_stage)[16 * b + tid] = unpack_val(pk);
        }

        if (t == S_LEN - 1) break;   // last h published; nothing left to read

        // ---- poll: thread tid waits for pair tid (tag+data in one 4-B word) ----
        if (!own) {
            const unsigned tag = (unsigned)(t + 1);
            const unsigned* p = &pairs[(size_t)(t & 1) * H_DIM + tid];
            unsigned pk;
            for (;;) {
                pk = __hip_atomic_load(p, __ATOMIC_RELAXED, __HIP_MEMORY_SCOPE_AGENT);
                if ((pk >> 16) == tag) break;
                __builtin_amdgcn_s_sleep(1);
            }
            ((float*)h_stage)[tid] = unpack_val(pk);
        }
        __syncthreads();
    }
}

// Final head: out = fc2( relu( fc1( relu(h_{S-1}) ) ) ). h_{S-1} is in pairs
// slot 1 ((S-1)&1). Kernel-boundary ordering makes plain loads safe.
__global__ __launch_bounds__(256) void fc_head(
    const unsigned* __restrict__ pairs,
    const float* __restrict__ fc1_w,  // [128, 1024]
    const float* __restrict__ fc1_b,  // [128]
    const float* __restrict__ fc2_w,  // [128]
    const float* __restrict__ fc2_b,  // [1]
    float* __restrict__ out)
{
    const int tid = threadIdx.x;
    __shared__ float4 hr4[H_DIM / 4];
    __shared__ float  partial[256];
    __shared__ float  r1[128];

    // extract fp16 h values from slot-1 pairs (4 pairs per thread)
    const uint4 pa = ((const uint4*)(pairs + H_DIM))[tid];
    float4 hv = make_float4(__half2float(__ushort_as_half((unsigned short)(pa.x & 0xFFFFu))),
                            __half2float(__ushort_as_half((unsigned short)(pa.y & 0xFFFFu))),
                            __half2float(__ushort_as_half((unsigned short)(pa.z & 0xFFFFu))),
                            __half2float(__ushort_as_half((unsigned short)(pa.w & 0xFFFFu))));
    hv.x = fmaxf(hv.x, 0.f); hv.y = fmaxf(hv.y, 0.f);
    hv.z = fmaxf(hv.z, 0.f); hv.w = fmaxf(hv.w, 0.f);
    hr4[tid] = hv;
    __syncthreads();

    const int row = tid & 127, half = tid >> 7;
    const float4* wrow = (const float4*)(fc1_w + (size_t)row * H_DIM) + half * 128;
    float a0 = 0.f, a1 = 0.f;
    #pragma unroll 4
    for (int i = 0; i < 128; i += 2) {
        const float4 w0 = wrow[i],     h0 = hr4[half * 128 + i];
        const float4 w1 = wrow[i + 1], h1 = hr4[half * 128 + i + 1];
        a0 += w0.x * h0.x + w0.y * h0.y + w0.z * h0.z + w0.w * h0.w;
        a1 += w1.x * h1.x + w1.y * h1.y + w1.z * h1.z + w1.w * h1.w;
    }
    partial[tid] = a0 + a1;
    __syncthreads();
    if (tid < 128) {
        const float s = partial[tid] + partial[tid + 128] + fc1_b[tid];
        r1[tid] = fmaxf(s, 0.f);
    }
    __syncthreads();
    if (tid < 64) {
        float v = r1[tid] * fc2_w[tid] + r1[tid + 64] * fc2_w[tid + 64];
        #pragma unroll
        for (int off = 32; off > 0; off >>= 1) v += __shfl_xor(v, off, 64);
        if (tid == 0) out[0] = v + fc2_b[0];
    }
}

extern "C" void kernel_launch(void* const* d_in, const int* in_sizes, int n_in,
                              void* d_out, int out_size, void* d_ws, size_t ws_size,
                              hipStream_t stream) {
    (void)in_sizes; (void)n_in; (void)out_size; (void)ws_size;
    const float* xseq  = (const float*)d_in[0];
    const float* W_ih  = (const float*)d_in[1];
    const float* W_hh  = (const float*)d_in[2];
    const float* b_ih  = (const float*)d_in[3];
    const float* b_hh  = (const float*)d_in[4];
    const float* fc1_w = (const float*)d_in[5];
    const float* fc1_b = (const float*)d_in[6];
    const float* fc2_w = (const float*)d_in[7];
    const float* fc2_b = (const float*)d_in[8];
    unsigned* pairs = (unsigned*)d_ws;

    lstm_persistent<<<NBLK, NTHR, 0, stream>>>(xseq, W_ih, W_hh, b_ih, b_hh, pairs);
    fc_head<<<1, 256, 0, stream>>>(pairs, fc1_w, fc1_b, fc2_w, fc2_b, (float*)d_out);
}